// Round 5
// baseline (24.116 us; speedup 1.0000x reference)
//
#include <hip/hip_runtime.h>
#include <hip/hip_bf16.h>

#define NBATCH 512
#define NS 66
#define ND 304
#define NK 128

#define XROWS 80           // 5 s-tiles of 16 (rows 66..79 garbage-but-contained)
#define XSTRIDE_B 640      // 320 bf16 per row (K padded 304->320)
#define XBYTES (XROWS * XSTRIDE_B)          // 51200
#define TSTRIDE_B 256      // 128 bf16 per row
#define TBYTES (XROWS * TSTRIDE_B)          // 20480
#define NTHREADS 512       // 8 waves

#define WCOLS 320                            // padded W columns (bf16)
#define WBYTES (NK * WCOLS * 2)              // 81920

typedef __attribute__((ext_vector_type(8))) short bf16x8;
typedef __attribute__((ext_vector_type(4))) short s16x4;
typedef __attribute__((ext_vector_type(4))) float f32x4;

__device__ __forceinline__ short f2bf(float x) {
    return __builtin_bit_cast(short, __float2bfloat16(x));
}

// 15 upper-triangle 16x16 tiles of G: 5 diagonal first, then 10 strict-upper.
__device__ const int TI_LUT[15] = {0,1,2,3,4, 0,0,0,0,1,1,1,2,2,3};
__device__ const int TJ_LUT[15] = {0,1,2,3,4, 1,2,3,4,2,3,4,3,4,4};

// ---- prologue: W f32 [128][304] -> bf16 [128][320] (pad cols zeroed) ----
__global__ __launch_bounds__(256) void wconvert(const float* __restrict__ W,
                                                short* __restrict__ Wb) {
    const int idx = blockIdx.x * 256 + threadIdx.x;   // one thread per 8 cols
    if (idx >= NK * (WCOLS / 8)) return;
    const int r  = idx / (WCOLS / 8);
    const int c0 = (idx % (WCOLS / 8)) * 8;
    bf16x8 f = {0, 0, 0, 0, 0, 0, 0, 0};
    if (c0 < ND) {                                    // 304 % 8 == 0: full groups
        const float4 p0 = *reinterpret_cast<const float4*>(W + r * ND + c0);
        const float4 p1 = *reinterpret_cast<const float4*>(W + r * ND + c0 + 4);
        f[0] = f2bf(p0.x); f[1] = f2bf(p0.y); f[2] = f2bf(p0.z); f[3] = f2bf(p0.w);
        f[4] = f2bf(p1.x); f[5] = f2bf(p1.y); f[6] = f2bf(p1.z); f[7] = f2bf(p1.w);
    }
    *reinterpret_cast<bf16x8*>(Wb + r * WCOLS + c0) = f;
}

template <bool WPRE>
__global__ __launch_bounds__(NTHREADS, 4) void treeprobe_mfma(
    const float* __restrict__ x,   // [512][66][304]
    const float* __restrict__ W,   // [128][304] (fallback path only)
    const short* __restrict__ Wb,  // [128][320] bf16 (WPRE path)
    float* __restrict__ out)       // [512][66][66]
{
    __shared__ __align__(16) char lds[XBYTES + TBYTES + 80 * 4];
    char* const t_lds = lds + XBYTES;
    float* const norms = (float*)(lds + XBYTES + TBYTES);

    const int tid   = threadIdx.x;
    const int batch = blockIdx.x;
    const int lane  = tid & 63;
    const int wv    = tid >> 6;     // wave 0..7
    const int lr    = lane & 15;
    const int lg    = lane >> 4;    // 0..3

    const float* __restrict__ xb = x + (size_t)batch * NS * ND;

    // ---- 1) issue ALL x global loads up-front (66*76 = 5016 float4) ----
    float4 aA[6], aB[5];
#pragma unroll
    for (int i = 0; i < 6; ++i) {
        const int e = tid + i * NTHREADS;
        aA[i] = (e < 2640)
            ? *reinterpret_cast<const float4*>(xb + (e / 40) * ND + (e % 40) * 4)
            : make_float4(0.f, 0.f, 0.f, 0.f);
    }
#pragma unroll
    for (int i = 0; i < 5; ++i) {
        const int e = tid + i * NTHREADS;
        aB[i] = (e < 2376)
            ? *reinterpret_cast<const float4*>(xb + (e / 36) * ND + 160 + (e % 36) * 4)
            : make_float4(0.f, 0.f, 0.f, 0.f);
    }

    // ---- 2) W fragments: direct bf16 loads (L2-hot) or f32 convert fallback ----
    // A-frag: idx = lane&15 (W row = t col), k = kk*32 + lg*8 + i (8 contiguous)
    bf16x8 wfrag[10];
    const int wc = wv * 16 + lr;                      // W row 0..127
    if constexpr (WPRE) {
#pragma unroll
        for (int kk = 0; kk < 10; ++kk)
            wfrag[kk] = *reinterpret_cast<const bf16x8*>(
                Wb + wc * WCOLS + kk * 32 + lg * 8);
    } else {
        const float* __restrict__ wr = W + wc * ND;
#pragma unroll
        for (int kk = 0; kk < 10; ++kk) {
            const int k0 = kk * 32 + lg * 8;
            bf16x8 f = {0, 0, 0, 0, 0, 0, 0, 0};
            if (k0 < ND) {
                const float4 p0 = *reinterpret_cast<const float4*>(wr + k0);
                const float4 p1 = *reinterpret_cast<const float4*>(wr + k0 + 4);
                f[0] = f2bf(p0.x); f[1] = f2bf(p0.y);
                f[2] = f2bf(p0.z); f[3] = f2bf(p0.w);
                f[4] = f2bf(p1.x); f[5] = f2bf(p1.y);
                f[6] = f2bf(p1.z); f[7] = f2bf(p1.w);
            }
            wfrag[kk] = f;
        }
    }

    // ---- 3) zero-fill pad regions (rows 66..79 full; k-pad of rows 0..65) ----
    for (int i = tid; i < 560; i += NTHREADS) {
        const int row = 66 + i / 40;
        *reinterpret_cast<f32x4*>(lds + row * XSTRIDE_B + (i % 40) * 16) =
            (f32x4){0.f, 0.f, 0.f, 0.f};
    }
    for (int i = tid; i < 132; i += NTHREADS) {
        const int row = i >> 1;
        const int byte = (row * XSTRIDE_B + 608 + (i & 1) * 16) ^ ((row & 7) << 4);
        *reinterpret_cast<f32x4*>(lds + byte) = (f32x4){0.f, 0.f, 0.f, 0.f};
    }

    // ---- 4) convert + write x to LDS (swizzled) ----
#pragma unroll
    for (int i = 0; i < 6; ++i) {
        const int e = tid + i * NTHREADS;
        if (e < 2640) {
            const int s = e / 40;
            const int f = (e % 40) * 4;
            const int byte = (s * XSTRIDE_B + f * 2) ^ ((s & 7) << 4);
            s16x4 sv;
            sv[0] = f2bf(aA[i].x); sv[1] = f2bf(aA[i].y);
            sv[2] = f2bf(aA[i].z); sv[3] = f2bf(aA[i].w);
            *reinterpret_cast<s16x4*>(lds + byte) = sv;
        }
    }
#pragma unroll
    for (int i = 0; i < 5; ++i) {
        const int e = tid + i * NTHREADS;
        if (e < 2376) {
            const int s = e / 36;
            const int f = 160 + (e % 36) * 4;
            const int byte = (s * XSTRIDE_B + f * 2) ^ ((s & 7) << 4);
            s16x4 sv;
            sv[0] = f2bf(aB[i].x); sv[1] = f2bf(aB[i].y);
            sv[2] = f2bf(aB[i].z); sv[3] = f2bf(aB[i].w);
            *reinterpret_cast<s16x4*>(lds + byte) = sv;
        }
    }
    __syncthreads();

    // ---- 5) phase 1: t = x . W^T, swapped operands (10 kk, no mid barrier) ----
    f32x4 acc[5];
#pragma unroll
    for (int st = 0; st < 5; ++st) acc[st] = (f32x4){0.f, 0.f, 0.f, 0.f};

#pragma unroll
    for (int kk = 0; kk < 10; ++kk) {
        bf16x8 a[5];
#pragma unroll
        for (int st = 0; st < 5; ++st) {
            const int row = st * 16 + lr;
            const int byte = (row * XSTRIDE_B + kk * 64 + lg * 16) ^ ((row & 7) << 4);
            a[st] = *reinterpret_cast<const bf16x8*>(lds + byte);
        }
#pragma unroll
        for (int st = 0; st < 5; ++st)
            acc[st] = __builtin_amdgcn_mfma_f32_16x16x32_bf16(
                wfrag[kk], a[st], acc[st], 0, 0, 0);
    }

    // ---- 6) write t (bf16, swizzled, 8B-packed) ----
    // swapped-operand D: col(lane&15)=s-in-tile, row(lg*4+r)=t-col-in-tile
#pragma unroll
    for (int st = 0; st < 5; ++st) {
        const int s = st * 16 + lr;
        const int c0 = wv * 16 + lg * 4;
        const int byte = (s * TSTRIDE_B + c0 * 2) ^ ((s & 7) << 4);
        s16x4 sv;
        sv[0] = f2bf(acc[st][0]); sv[1] = f2bf(acc[st][1]);
        sv[2] = f2bf(acc[st][2]); sv[3] = f2bf(acc[st][3]);
        *reinterpret_cast<s16x4*>(t_lds + byte) = sv;
    }
    __syncthreads();

    // ---- 7) phase 2: 15 upper-triangle G tiles in registers ----
    const int idx0 = wv;            // 0..7  (5 diagonal + 3 upper)
    const int idx1 = wv + 8;        // 8..14 (upper), wv==7 -> invalid
    const int ti0 = TI_LUT[idx0], tj0 = TJ_LUT[idx0];

    f32x4 g0 = (f32x4){0.f, 0.f, 0.f, 0.f};
#pragma unroll
    for (int kk = 0; kk < 4; ++kk) {
        const int ra = ti0 * 16 + lr;
        const int ba = (ra * TSTRIDE_B + kk * 64 + lg * 16) ^ ((ra & 7) << 4);
        const int rb = tj0 * 16 + lr;
        const int bb = (rb * TSTRIDE_B + kk * 64 + lg * 16) ^ ((rb & 7) << 4);
        g0 = __builtin_amdgcn_mfma_f32_16x16x32_bf16(
            *reinterpret_cast<const bf16x8*>(t_lds + ba),
            *reinterpret_cast<const bf16x8*>(t_lds + bb), g0, 0, 0, 0);
    }
    if (wv < 5) {                   // diagonal: extract norms
#pragma unroll
        for (int r = 0; r < 4; ++r)
            if (lr == lg * 4 + r) norms[wv * 16 + lr] = g0[r];
    }

    f32x4 g1 = (f32x4){0.f, 0.f, 0.f, 0.f};
    int ti1 = 0, tj1 = 0;
    if (idx1 < 15) {
        ti1 = TI_LUT[idx1]; tj1 = TJ_LUT[idx1];
#pragma unroll
        for (int kk = 0; kk < 4; ++kk) {
            const int ra = ti1 * 16 + lr;
            const int ba = (ra * TSTRIDE_B + kk * 64 + lg * 16) ^ ((ra & 7) << 4);
            const int rb = tj1 * 16 + lr;
            const int bb = (rb * TSTRIDE_B + kk * 64 + lg * 16) ^ ((rb & 7) << 4);
            g1 = __builtin_amdgcn_mfma_f32_16x16x32_bf16(
                *reinterpret_cast<const bf16x8*>(t_lds + ba),
                *reinterpret_cast<const bf16x8*>(t_lds + bb), g1, 0, 0, 0);
        }
    }
    __syncthreads();

    // ---- 8) epilogue: out[i][j] = norms[i] + norms[j] - 2 G[i][j] (+mirror) ----
    float* __restrict__ ob = out + (size_t)batch * NS * NS;

    {   // tile idx0
        const int j = tj0 * 16 + lr;
        const float nj = norms[j];
        float v[4];
#pragma unroll
        for (int r = 0; r < 4; ++r) {
            const int i = ti0 * 16 + lg * 4 + r;
            v[r] = norms[i] + nj - 2.f * g0[r];
            if (i < NS && j < NS) ob[i * NS + j] = v[r];
        }
        if (ti0 != tj0 && j < NS) {             // upper tiles of idx0 = 5,6,7
            const int i0 = ti0 * 16 + lg * 4;   // i0..i0+3 contiguous, i0+3 < 64 < NS
            *reinterpret_cast<float2*>(ob + j * NS + i0)     = make_float2(v[0], v[1]);
            *reinterpret_cast<float2*>(ob + j * NS + i0 + 2) = make_float2(v[2], v[3]);
        }
    }
    if (idx1 < 15) {
        const int j = tj1 * 16 + lr;
        const float nj = norms[j];
        float v[4];
#pragma unroll
        for (int r = 0; r < 4; ++r) {
            const int i = ti1 * 16 + lg * 4 + r;
            v[r] = norms[i] + nj - 2.f * g1[r];
            if (i < NS && j < NS) ob[i * NS + j] = v[r];
        }
        if (j < NS) {                           // strict-upper: vectorized mirror
            const int i0 = ti1 * 16 + lg * 4;   // ti1 <= 3 -> i0+3 <= 63 < NS
            *reinterpret_cast<float2*>(ob + j * NS + i0)     = make_float2(v[0], v[1]);
            *reinterpret_cast<float2*>(ob + j * NS + i0 + 2) = make_float2(v[2], v[3]);
        }
    }
}

extern "C" void kernel_launch(void* const* d_in, const int* in_sizes, int n_in,
                              void* d_out, int out_size, void* d_ws, size_t ws_size,
                              hipStream_t stream) {
    const float* x = (const float*)d_in[0];   // (512, 66, 304) f32
    const float* W = (const float*)d_in[1];   // (128, 304) f32
    // d_in[2] = b : cancels in the pairwise difference, unused.
    float* out = (float*)d_out;               // (512, 66, 66) f32

    if (ws_size >= (size_t)WBYTES) {
        short* Wb = (short*)d_ws;
        wconvert<<<(NK * (WCOLS / 8) + 255) / 256, 256, 0, stream>>>(W, Wb);
        treeprobe_mfma<true><<<NBATCH, NTHREADS, 0, stream>>>(x, W, Wb, out);
    } else {
        treeprobe_mfma<false><<<NBATCH, NTHREADS, 0, stream>>>(x, W, nullptr, out);
    }
}